// Round 12
// baseline (414.522 us; speedup 1.0000x reference)
//
#include <hip/hip_runtime.h>
#include <hip/hip_bf16.h>

// 2-layer 4-direction MDLSTM, fused. B=256, Wd=2048, OUT=11.
// R19: POSITION-SPLIT: 2 blocks per batch (grid 512), each owns 1024
// positions -> LDS 79.6 KB/block -> 2 blocks/CU = 4 waves/SIMD of the
// proven R14 512-thread structure. R14/R18 at 2 waves/SIMD idle ~30%
// (VALUBusy 67-72) vs 84-85% at 4 waves (R9/R11); NTHR=1024 path is dead
// (allocator pins VGPR=64 and spills; R15-R17). Cross-half L1->L2 dep
// solved IN-BLOCK: each block synthesizes the 40-pos y-ext strip its L2
// boundary warms need: outer-dir wave-7 chains EXTEND 40 exact steps past
// the inner boundary; inner-dir wave-0 chains run 80-warm, last 40 steps
// accumulating (40-warmed, error ~e^-29 << f16 quantum). No inter-block
// comm. True boundaries keep garbage-warm+rezero (proven R12-R18).
// Windows: acc/y = POS+-40 (1104 rows), x = POS+-80 (1184); all warm/ext
// accesses verified in-window (no clamps needed).
// R14 carried: unit-per-lane, 4 chains/wave, pure-VALU rotate-reduce
// distribution (2 quad_perm + cvt_pkrtz; 7x dpp row_ror:2; U pre-permuted,
// 8 slots, pairs 6/7 zero; direction via runtime dpp probe). DS crossbar
// on the chain banned (R12/R13). f32 LDS atomic acc; f16-pair y strip;
// exp2-folded activations.

#define NOUT 11
#define WD 2048
#define NB 256
#define NBLK (NB * 2)
#define ROW 12
#define POS 1024       // positions per block
#define AEXT 40        // acc/y window extension each side
#define XEXT 80        // x window extension each side
#define ANPOS (POS + 2 * AEXT)   // 1104
#define XWN (POS + 2 * XEXT)     // 1184
#define ACCN (ANPOS * ROW)       // 13248 f32 = 52992 B
#define YROW 6
#define YPAD 12
#define YBFN (ANPOS * YROW + 2 * YPAD)  // 6648 u32 = 26592 B

#define NTHR 512
#define CHUNK 128
#define WARM 40

typedef float f2 __attribute__((ext_vector_type(2)));
typedef float f4 __attribute__((ext_vector_type(4)));
typedef unsigned int u32;
typedef u32 u32x2 __attribute__((ext_vector_type(2)));
typedef __fp16 h2 __attribute__((ext_vector_type(2)));

#define LOG2E 1.4426950408889634f

union UH { u32 u; h2 h; };
__device__ __forceinline__ u32 h2u(h2 v) { UH x; x.h = v; return x.u; }
__device__ __forceinline__ h2 u2h(u32 v) { UH x; x.u = v; return x.h; }

template <int CTRL>
__device__ __forceinline__ float dppf(float v) {
  return __int_as_float(__builtin_amdgcn_update_dpp(
      __float_as_int(v), __float_as_int(v), CTRL, 0xF, 0xF, false));
}
__device__ __forceinline__ h2 rorh(h2 v) {
  return u2h((u32)__builtin_amdgcn_update_dpp(
      (int)h2u(v), (int)h2u(v), 0x122, 0xF, 0xF, false));
}
__device__ __forceinline__ float rcp_(float x) { return __builtin_amdgcn_rcpf(x); }
__device__ __forceinline__ float exp2_(float x) { return __builtin_amdgcn_exp2f(x); }
__device__ __forceinline__ float dot2(h2 a, h2 b, float c) {
  return __builtin_amdgcn_fdot2(a, b, c, false);
}

// WRP: runtime per-lane accumulate predicate.
// In scope: hj, cpr, giI/F/O/A, ao, ad, UpI/F/O/A[8], acc.
#define STEP(WRP, ...)                                                         \
  do {                                                                         \
    const float hEv = dppf<0xA0>(hj);                                          \
    const float hOd = dppf<0xF5>(hj);                                          \
    h2 rv = __builtin_amdgcn_cvt_pkrtz(hEv, hOd);                              \
    __VA_ARGS__                                                                \
    float gI = dot2(rv, UpI[0], giI);                                          \
    float gF = dot2(rv, UpF[0], giF);                                          \
    float gO = dot2(rv, UpO[0], giO);                                          \
    float gA = dot2(rv, UpA[0], giA);                                          \
    _Pragma("unroll")                                                          \
    for (int s = 1; s < 8; ++s) {                                              \
      rv = rorh(rv);                                                           \
      gI = dot2(rv, UpI[s], gI);                                               \
      gF = dot2(rv, UpF[s], gF);                                               \
      gO = dot2(rv, UpO[s], gO);                                               \
      gA = dot2(rv, UpA[s], gA);                                               \
    }                                                                          \
    const float sI = rcp_(1.0f + exp2_(gI));                                   \
    const float sF = rcp_(1.0f + exp2_(gF));                                   \
    const float sO = rcp_(1.0f + exp2_(gO));                                   \
    const float sA = rcp_(1.0f + exp2_(gA));                                   \
    const float taS = fmaf(-4.0f * LOG2E, sA, 2.0f * LOG2E);                   \
    cpr = fmaf(sF, cpr, sI * taS);                                             \
    const float r2t = rcp_(1.0f + exp2_(cpr));                                 \
    const float sO2 = sO + sO;                                                 \
    hj = fmaf(sO2, r2t, -sO);                                                  \
    if (WRP) atomicAdd(&acc[ao], hj);                                          \
    ao += ad;                                                                  \
  } while (0)

#define CP giI = gnI; giF = gnF; giO = gnO; giA = gnA;

__global__ __launch_bounds__(NTHR, 1) void mdlstm_fused(
    const float* __restrict__ x, const float* __restrict__ W0,
    const float* __restrict__ U0, const float* __restrict__ b0,
    const float* __restrict__ W1, const float* __restrict__ U1,
    const float* __restrict__ b1, float* __restrict__ out) {
  __shared__ __align__(16) float acc[ACCN];  // 52.0 KB
  __shared__ __align__(16) u32 ybf[YBFN];    // 26.0 KB (xw f32 | y f16-pairs)

  const int tid = threadIdx.x;
  const int bid = blockIdx.x;
  const int b = bid >> 1;
  const int half = bid & 1;
  const int POFF = half << 10;
  const int XOFFR = POFF - XEXT;
  const int AOFFR = POFF - AEXT;
  float* xw = (float*)ybf;

  // ---- Phase A: height-sum x window -> xw; zero acc ----
  {
    const float* xb = x + (size_t)b * 32 * WD;
    f4* xw4 = (f4*)xw;
    for (int i2 = tid; i2 < XWN / 4; i2 += NTHR) {
      const int phys = XOFFR + 4 * i2;
      f4 s = {0.f, 0.f, 0.f, 0.f};
      if ((unsigned)phys < 2048u) {  // window offsets are mult of 4
        s = *(const f4*)(xb + phys);
#pragma unroll
        for (int h = 1; h < 32; ++h) s += *(const f4*)(xb + h * WD + phys);
      }
      xw4[i2] = s;
    }
    f4* a4 = (f4*)acc;
    const f4 z = {0.f, 0.f, 0.f, 0.f};
    for (int i = tid; i < ACCN / 4; i += NTHR) a4[i] = z;
  }
  __syncthreads();

  const int lane = tid & 63;
  const int wv = tid >> 6;      // 0..7 = chunk index
  const int d = lane >> 4;      // direction 0..3 (group)
  const int u = lane & 15;      // unit (11..15 dummy)
  const int ck = wv;
  const bool fwd = ((d & 1) == 0);
  const bool real = (u <= 10);
  const bool wr = real;
  // outer dirs: true-boundary side of this block (garbage-warm at ck0,
  // and extend past the inner boundary at ck7).
  const bool outerG = (half == 0) ? fwd : !fwd;
  const bool rz0 = (wv == 0) && outerG;
  const bool wrm = wr && (wv == 0) && !outerG;  // warm-acc (y-ext, inner)
  const bool wre = wr && outerG;                // ext-acc (y-ext, wave 7)
  // gate cols: i:0-10 f:11-21 o:33-43 a:44-54; dummy -> col 54, scl 0
  const int colI = real ? u : 54;
  const int colF = real ? (11 + u) : 54;
  const int colO = real ? (33 + u) : 54;
  const int colA = real ? (44 + u) : 54;
  const float sclS = real ? -LOG2E : 0.f;
  const float sclA = real ? (-2.f * LOG2E) : 0.f;

  // Rotation-direction probe (row_ror:2 semantics).
  const int li = lane & 15;
  const int pv = __builtin_amdgcn_update_dpp(0, li, 0x122, 0xF, 0xF, false);
  const bool rplus = (pv == ((li + 2) & 15));
  const int p0 = li >> 1;

  const int s0 = fwd ? (POFF + ck * CHUNK) : (POFF + POS - 1 - ck * CHUNK);
  const int wl1 = (wv == 0) ? (WARM + AEXT) : WARM;  // L1 warm (80 on wv0)
  const int st1 = fwd ? (s0 - wl1) : (s0 + wl1);
  const int st2 = fwd ? (s0 - WARM) : (s0 + WARM);
  const int xd = fwd ? 1 : -1;
  const int ad = fwd ? ROW : -ROW;
  const int qd = fwd ? 3 : -3;
  const int pre = wl1 - WARM;  // 40 on wave 0, else 0

  auto loadUrot = [&](const float* U, int col, float scl, h2* Up) {
#pragma unroll
    for (int s = 0; s < 8; ++s) {
      const int pr = rplus ? ((p0 + s) & 7) : ((p0 + 8 - s) & 7);
      const int r0 = 2 * pr, r1 = r0 + 1;
      const int rr0 = (r0 <= 10) ? r0 : 0;
      const int rr1 = (r1 <= 10) ? r1 : 0;
      float a = U[(d * NOUT + rr0) * 55 + col] * scl;
      float bb = U[(d * NOUT + rr1) * 55 + col] * scl;
      a = (r0 <= 10) ? a : 0.f;
      bb = (r1 <= 10) ? bb : 0.f;
      Up[s] = __builtin_amdgcn_cvt_pkrtz(a, bb);
    }
  };
  auto loadW = [&](const float* U, int col, float scl, h2* Up) {
    float uv[12];
#pragma unroll
    for (int s = 0; s < NOUT; ++s) uv[s] = U[(d * NOUT + s) * 55 + col] * scl;
    uv[11] = 0.f;
#pragma unroll
    for (int k = 0; k < 6; ++k)
      Up[k] = __builtin_amdgcn_cvt_pkrtz(uv[2 * k], uv[2 * k + 1]);
  };

  // ---- Phase B: layer-1 scan ----
  {
    h2 UpI[8], UpF[8], UpO[8], UpA[8];
    loadUrot(U0, colI, sclS, UpI);
    loadUrot(U0, colF, sclS, UpF);
    loadUrot(U0, colO, sclS, UpO);
    loadUrot(U0, colA, sclA, UpA);
    const float WcI = W0[d * 55 + colI] * sclS;
    const float WcF = W0[d * 55 + colF] * sclS;
    const float WcO = W0[d * 55 + colO] * sclS;
    const float WcA = W0[d * 55 + colA] * sclA;
    const float bcI = b0[d * 55 + colI] * sclS;
    const float bcF = b0[d * 55 + colF] * sclS;
    const float bcO = b0[d * 55 + colO] * sclS;
    const float bcA = b0[d * 55 + colA] * sclA;

    int xo = st1 - XOFFR;            // local x index; in-window by design
    int ao = (st1 - AOFFR) * ROW + u;  // may start OOB; unused until valid
    float hj = 0.f, cpr = 0.f;
    float gnI = 0.f, gnF = 0.f, gnO = 0.f, gnA = 0.f;
    const float xc = xw[xo];
    xo += xd;
    float giI = fmaf(xc, WcI, bcI);
    float giF = fmaf(xc, WcF, bcF);
    float giO = fmaf(xc, WcO, bcO);
    float giA = fmaf(xc, WcA, bcA);
    float xn = xw[xo];
    xo += xd;

#define PREP1                                                                  \
    const float xn2 = xw[xo];                                                  \
    xo += xd;                                                                  \
    gnI = fmaf(xn, WcI, bcI);                                                  \
    gnF = fmaf(xn, WcF, bcF);                                                  \
    gnO = fmaf(xn, WcO, bcO);                                                  \
    gnA = fmaf(xn, WcA, bcA);                                                  \
    xn = xn2;

    for (int t = 0; t < pre; t += 2) {        // wv0 pre-warm (no acc)
      STEP(false, PREP1); CP;
      STEP(false, PREP1); CP;
    }
    for (int t = 0; t < WARM; t += 2) {       // warm; inner wv0 accumulates
      STEP(wrm, PREP1); CP;
      STEP(wrm, PREP1); CP;
    }
    hj = rz0 ? 0.f : hj;                      // true-boundary rezero
    cpr = rz0 ? 0.f : cpr;
    for (int t = 0; t < CHUNK; t += 2) {
      STEP(wr, PREP1); CP;
      STEP(wr, PREP1); CP;
    }
    if (wv == 7) {                            // outer dirs extend into y-ext
      for (int t = 0; t < AEXT; t += 2) {
        STEP(wre, PREP1); CP;
        STEP(wre, PREP1); CP;
      }
    }
#undef PREP1
  }
  __syncthreads();

  // ---- Phase C: pack acc -> f16-pair ybf (+ zero guards); re-zero acc ----
  {
    const f2* a2 = (const f2*)acc;
    for (int i = tid; i < ANPOS * YROW; i += NTHR) {
      const f2 v = a2[i];
      ybf[YPAD + i] = h2u(__builtin_amdgcn_cvt_pkrtz(v.x, v.y));
    }
    if (tid < YPAD) {
      ybf[tid] = 0;
      ybf[YPAD + ANPOS * YROW + tid] = 0;
    }
  }
  __syncthreads();
  {
    f4* a4 = (f4*)acc;
    const f4 z = {0.f, 0.f, 0.f, 0.f};
    for (int i = tid; i < ACCN / 4; i += NTHR) a4[i] = z;
  }
  __syncthreads();

  // ---- Phase D: layer-2 scan ----
  {
    h2 UpI[8], UpF[8], UpO[8], UpA[8];
    h2 WpI[6], WpF[6], WpO[6], WpA[6];
    loadUrot(U1, colI, sclS, UpI);
    loadUrot(U1, colF, sclS, UpF);
    loadUrot(U1, colO, sclS, UpO);
    loadUrot(U1, colA, sclA, UpA);
    loadW(W1, colI, sclS, WpI);
    loadW(W1, colF, sclS, WpF);
    loadW(W1, colO, sclS, WpO);
    loadW(W1, colA, sclA, WpA);
    const float bcI = b1[d * 55 + colI] * sclS;
    const float bcF = b1[d * 55 + colF] * sclS;
    const float bcO = b1[d * 55 + colO] * sclS;
    const float bcA = b1[d * 55 + colA] * sclA;

    const u32x2* yv = (const u32x2*)ybf;  // local row r -> yv[3r+6 .. 3r+8]
    int q = 3 * (st2 - AOFFR) + 6;        // in-window by design

    auto GIc = [&](const h2* Wp, float bc, u32x2 r0, u32x2 r1,
                   u32x2 r2) -> float {
      float A = dot2(u2h(r0.x), Wp[0], bc);
      A = dot2(u2h(r0.y), Wp[1], A);
      A = dot2(u2h(r1.x), Wp[2], A);
      A = dot2(u2h(r1.y), Wp[3], A);
      A = dot2(u2h(r2.x), Wp[4], A);
      A = dot2(u2h(r2.y), Wp[5], A);
      return A;
    };

    u32x2 c0 = yv[q], c1 = yv[q + 1], c2 = yv[q + 2];
    q += qd;
    u32x2 pr0 = yv[q], pr1 = yv[q + 1], pr2 = yv[q + 2];
    q += qd;

    float giI = GIc(WpI, bcI, c0, c1, c2);
    float giF = GIc(WpF, bcF, c0, c1, c2);
    float giO = GIc(WpO, bcO, c0, c1, c2);
    float giA = GIc(WpA, bcA, c0, c1, c2);

    int ao = (st2 - AOFFR) * ROW + u;
    float hj = 0.f, cpr = 0.f;
    float gnI = 0.f, gnF = 0.f, gnO = 0.f, gnA = 0.f;

#define PREP2                                                                  \
    const u32x2 n0 = yv[q];                                                    \
    const u32x2 n1 = yv[q + 1];                                                \
    const u32x2 n2 = yv[q + 2];                                                \
    q += qd;                                                                   \
    gnI = GIc(WpI, bcI, pr0, pr1, pr2);                                        \
    gnF = GIc(WpF, bcF, pr0, pr1, pr2);                                        \
    gnO = GIc(WpO, bcO, pr0, pr1, pr2);                                        \
    gnA = GIc(WpA, bcA, pr0, pr1, pr2);                                        \
    pr0 = n0;                                                                  \
    pr1 = n1;                                                                  \
    pr2 = n2;

    for (int t = 0; t < WARM; t += 2) {       // boundary warms read y-ext
      STEP(false, PREP2); CP;
      STEP(false, PREP2); CP;
    }
    hj = rz0 ? 0.f : hj;
    cpr = rz0 ? 0.f : cpr;
    for (int t = 0; t < CHUNK; t += 2) {
      STEP(wr, PREP2); CP;
      STEP(wr, PREP2); CP;
    }
#undef PREP2
  }
  __syncthreads();

  // ---- Phase E: writeout out[b][j][POFF + w] = acc[(w+AEXT)*ROW + j] ----
  float* ob = out + (size_t)b * (NOUT * WD) + POFF;
  for (int i = tid; i < NOUT * POS; i += NTHR) {
    const int jj = i >> 10;
    const int w = i & (POS - 1);
    ob[jj * WD + w] = acc[(w + AEXT) * ROW + jj];
  }
}

extern "C" void kernel_launch(void* const* d_in, const int* in_sizes, int n_in,
                              void* d_out, int out_size, void* d_ws,
                              size_t ws_size, hipStream_t stream) {
  const float* x  = (const float*)d_in[0];
  const float* W0 = (const float*)d_in[1];
  const float* U0 = (const float*)d_in[2];
  const float* b0 = (const float*)d_in[3];
  const float* W1 = (const float*)d_in[4];
  const float* U1 = (const float*)d_in[5];
  const float* b1 = (const float*)d_in[6];
  float* out = (float*)d_out;

  mdlstm_fused<<<NBLK, NTHR, 0, stream>>>(x, W0, U0, b0, W1, U1, b1, out);
}